// Round 3
// baseline (104.270 us; speedup 1.0000x reference)
//
#include <hip/hip_runtime.h>

// Round 16: in-wave ILP attack. r14 (occupancy cap raise) and r15 (8->12
// resident waves/CU) were both null: the kernel is dependency-stall bound
// (per-wave issue ~1.2us vs ~40us wall; LDS-port/VALU/MFMA floors all <16us)
// and extra WAVES don't fill the stalls. Now each wave runs TWO tiles
// concurrently: 4 independent MFMA accumulator chains (dep distance 4),
// batched LDS reads (6-8 ds_read_b128 per s4 under one lgkm wait), 8
// independent epilogue FMA chains. Rect tiles pair in-band (t,t+1 share fj
// -> 24 reads/pair instead of 32, -25% LDS issue). Diag tiles pair (20,21),
// (22,23); tile 24 single on wave 0. VGPR ~220 -> __launch_bounds__(256,2):
// 2 waves/SIMD proved sufficient (r13); registers are spent on ILP instead.

#define NF 40
#define ED 64
#define AS 32
#define XS_STRIDE 68   // floats; 272 B rows, 16B-aligned, 4-bank rotate/row
#define SM_STRIDE 40   // shorts; 80 B rows, 16B-aligned, 20-bank rotate/row

typedef __attribute__((ext_vector_type(4))) float f32x4;
typedef __attribute__((ext_vector_type(16))) float f32x16;
typedef __attribute__((ext_vector_type(8))) short bf16x8;

union ABFrag { bf16x8 v; unsigned int u[4]; uint4 q; };

// bf16 round-half-up: bits(f)+0x8000 >> 16. == RNE except on exact ties.
__device__ __forceinline__ unsigned short bfbits_rn(float f) {
  return (unsigned short)((__float_as_uint(f) + 0x8000u) >> 16);
}
// pack2: (bf16(a)) | (bf16(b) << 16) in 3 VALU (2 adds + v_perm byte-pack).
__device__ __forceinline__ unsigned int pack2(float a, float b) {
  unsigned int ua = __float_as_uint(a) + 0x8000u;
  unsigned int ub = __float_as_uint(b) + 0x8000u;
  return __builtin_amdgcn_perm(ub, ua, 0x07060302u);
}
// split: hi = pack2(a,b); lo = pack2 of the exact residuals.
__device__ __forceinline__ void split_pack(float a, float b,
                                           unsigned int& hi, unsigned int& lo) {
  hi = pack2(a, b);
  float ra = a - __uint_as_float(hi << 16);
  float rb = b - __uint_as_float(hi & 0xffff0000u);
  lo = pack2(ra, rb);
}

__global__ __launch_bounds__(256, 2) void afm_kernel(
    const float* __restrict__ x, const float* __restrict__ attn_w,
    const float* __restrict__ attn_b, const float* __restrict__ proj_w,
    const float* __restrict__ proj_b, const float* __restrict__ fc_w,
    const float* __restrict__ fc_b, float* __restrict__ out) {
  __shared__ __align__(16) float xs[NF * XS_STRIDE];            // 10880 B
  __shared__ __align__(16) unsigned short Smh[NF * SM_STRIDE];  // 3200 B
  __shared__ float red[8];  // [0..3]: lsum partials, [4..7]: ypart partials

  const int tid = threadIdx.x;
  const int lane = tid & 63;
  const int wid = tid >> 6;
  const int quad = lane >> 4;
  const int col = lane & 15;
  const int half = lane >> 5;        // 32x32 MFMA k-half
  const int m32 = lane & 31;         // 32x32 MFMA row/col index
  const int i_off = m32 >> 3;        // rect-tile row-within-tile
  const int jr_off = m32 & 7;        // rect-tile col-within-tile
  const int row = blockIdx.x;
  const float* xg = x + row * (NF * ED);

  // ---- P1: stage x row (640 float4 across 256 threads), zero Smh.
#pragma unroll
  for (int v = 0; v < 3; ++v) {
    int e4 = v * 256 + tid;
    if (e4 < 640) {
      int f = e4 >> 4, c4 = e4 & 15;
      *(float4*)(xs + f * XS_STRIDE + c4 * 4) = *(const float4*)(xg + e4 * 4);
    }
  }
#pragma unroll
  for (int v = 0; v < 4; ++v) {      // 800 u32
    int e = v * 256 + tid;
    if (e < (NF * SM_STRIDE) / 2) ((unsigned int*)Smh)[e] = 0u;
  }

  // ---- per-lane constants (each wave computes its own identical copy).
  // A-frag (32x32x16): A[mrow=m32][k=half*8+e]; A = W^T -> w[d][a=m32].
  ABFrag fwh[4], fwl[4];
#pragma unroll
  for (int s4 = 0; s4 < 4; ++s4)
#pragma unroll
    for (int p = 0; p < 4; ++p) {
      int d = s4 * 16 + half * 8 + 2 * p;
      split_pack(attn_w[d * AS + m32], attn_w[(d + 1) * AS + m32],
                 fwh[s4].u[p], fwl[s4].u[p]);
    }
  // Epilogue constants: C/D row(reg) = (reg&3) + 8*(reg>>2) + 4*half.
  // ABV/Z16 feed the first MFMA C-operand of each chain (no acc-init movs).
  f32x16 ABV, Z16;
  float pwv[16];
#pragma unroll
  for (int r = 0; r < 16; ++r) {
    int arow = (r & 3) + 8 * (r >> 2) + 4 * half;
    ABV[r] = attn_b[arow];
    pwv[r] = proj_w[arow];
    Z16[r] = 0.f;
  }
  const float fcb = fc_b[0];

  // ---- diagonal-tile decode (once per lane): triu-of-8, 28 pairs + 4 pads.
  int dmm = (m32 < 28) ? m32 : 0;
  int da = 0;
  while (dmm >= 7 - da) { dmm -= 7 - da; ++da; }
  const int a_off = da;
  const int j_off = da + 1 + dmm;
  const bool dpad = (m32 >= 28);

  __syncthreads();  // B1: xs + Smh zeros ready

  // ---- shared epilogue: fused relu+proj dot, 4 independent FMA chains.
  auto epi = [&](const f32x16& a0, const f32x16& a1) -> float {
    float lg0 = 0.f, lg1 = 0.f, lg2 = 0.f, lg3 = 0.f;
#pragma unroll
    for (int r = 0; r < 4; ++r) {
      lg0 = fmaf(fmaxf(a0[r] + a1[r], 0.f), pwv[r], lg0);
      lg1 = fmaf(fmaxf(a0[r + 4] + a1[r + 4], 0.f), pwv[r + 4], lg1);
      lg2 = fmaf(fmaxf(a0[r + 8] + a1[r + 8], 0.f), pwv[r + 8], lg2);
      lg3 = fmaf(fmaxf(a0[r + 12] + a1[r + 12], 0.f), pwv[r + 12], lg3);
    }
    float lg = (lg0 + lg1) + (lg2 + lg3);
    lg += __shfl_xor(lg, 32);  // combine the two k-halves
    return lg;
  };

  float lsum = 0.f;

  // ---- dual-tile body: two 32x32x16 MFMA tiles on 4 independent acc
  // chains; sharedJ (rect pairs) skips tile B's j-loads (constant-folded
  // after inlining: call sites pass literal sharedJ).
  auto do_pair = [&](int fiA, int fjA, int fiB, int fjB, bool sharedJ,
                     bool vA, bool vB) {
    const float* xiA = xs + fiA * XS_STRIDE + half * 8;
    const float* xiB = xs + fiB * XS_STRIDE + half * 8;
    const float* xjA = xs + fjA * XS_STRIDE + half * 8;
    const float* xjB = xs + fjB * XS_STRIDE + half * 8;
    f32x16 aA0, aA1, aB0, aB1;
#pragma unroll
    for (int s4 = 0; s4 < 4; ++s4) {
      float4 jA0 = *(const float4*)(xjA + s4 * 16);
      float4 jA1 = *(const float4*)(xjA + s4 * 16 + 4);
      float4 iA0 = *(const float4*)(xiA + s4 * 16);
      float4 iA1 = *(const float4*)(xiA + s4 * 16 + 4);
      float4 iB0 = *(const float4*)(xiB + s4 * 16);
      float4 iB1 = *(const float4*)(xiB + s4 * 16 + 4);
      float4 jB0, jB1;
      if (sharedJ) {
        jB0 = jA0; jB1 = jA1;
      } else {
        jB0 = *(const float4*)(xjB + s4 * 16);
        jB1 = *(const float4*)(xjB + s4 * 16 + 4);
      }
      ABFrag ipA, ipB;  // B-frags: B[k=half*8+e][n=m32]
      ipA.u[0] = pack2(iA0.x * jA0.x, iA0.y * jA0.y);
      ipA.u[1] = pack2(iA0.z * jA0.z, iA0.w * jA0.w);
      ipA.u[2] = pack2(iA1.x * jA1.x, iA1.y * jA1.y);
      ipA.u[3] = pack2(iA1.z * jA1.z, iA1.w * jA1.w);
      ipB.u[0] = pack2(iB0.x * jB0.x, iB0.y * jB0.y);
      ipB.u[1] = pack2(iB0.z * jB0.z, iB0.w * jB0.w);
      ipB.u[2] = pack2(iB1.x * jB1.x, iB1.y * jB1.y);
      ipB.u[3] = pack2(iB1.z * jB1.z, iB1.w * jB1.w);
      if (s4 == 0) {
        aA0 = __builtin_amdgcn_mfma_f32_32x32x16_bf16(fwh[0].v, ipA.v, ABV, 0, 0, 0);
        aB0 = __builtin_amdgcn_mfma_f32_32x32x16_bf16(fwh[0].v, ipB.v, ABV, 0, 0, 0);
        aA1 = __builtin_amdgcn_mfma_f32_32x32x16_bf16(fwl[0].v, ipA.v, Z16, 0, 0, 0);
        aB1 = __builtin_amdgcn_mfma_f32_32x32x16_bf16(fwl[0].v, ipB.v, Z16, 0, 0, 0);
      } else {
        aA0 = __builtin_amdgcn_mfma_f32_32x32x16_bf16(fwh[s4].v, ipA.v, aA0, 0, 0, 0);
        aB0 = __builtin_amdgcn_mfma_f32_32x32x16_bf16(fwh[s4].v, ipB.v, aB0, 0, 0, 0);
        aA1 = __builtin_amdgcn_mfma_f32_32x32x16_bf16(fwl[s4].v, ipA.v, aA1, 0, 0, 0);
        aB1 = __builtin_amdgcn_mfma_f32_32x32x16_bf16(fwl[s4].v, ipB.v, aB1, 0, 0, 0);
      }
    }
    float lgA = epi(aA0, aA1);
    float lgB = epi(aB0, aB1);
    if (vA) {
      float e = __expf(lgA);
      Smh[fiA * SM_STRIDE + fjA] = bfbits_rn(e);
      lsum += e;
    }
    if (vB) {
      float e = __expf(lgB);
      Smh[fiB * SM_STRIDE + fjB] = bfbits_rn(e);
      lsum += e;
    }
  };

  // ---- P2: 12 pair-units round-robin across 4 waves; tile 24 on wave 0.
  // Units 0..9: rect pairs (tiles 2u, 2u+1) - same band, shared fj.
  // Units 10,11: diag pairs (chunks 0,1) and (chunks 2,3).
#pragma unroll
  for (int k = 0; k < 3; ++k) {
    const int u = wid + 4 * k;  // 0..11
    if (u < 10) {
      const int t = 2 * u;
      const int j0 = 1 + (t >= 2) + (t >= 6) + (t >= 12);        // uniform
      const int tb = (t >= 12) ? 12 : (t >= 6) ? 6 : (t >= 2) ? 2 : 0;
      const int fiA = (t - tb) * 4 + i_off;
      const int fj = j0 * 8 + jr_off;
      do_pair(fiA, fj, fiA + 4, fj, true, lane < 32, lane < 32);
    } else {
      const int kkA = 2 * (u - 10);  // chunks (0,1) or (2,3)
      const bool dv = (lane < 32) & !dpad;
      do_pair(8 * kkA + a_off, 8 * kkA + j_off,
              8 * (kkA + 1) + a_off, 8 * (kkA + 1) + j_off, false, dv, dv);
    }
  }
  if (wid == 0) {  // single diag tile 24 (chunk 4)
    const int fi = 32 + a_off;
    const int fj = 32 + j_off;
    const float* xi = xs + fi * XS_STRIDE + half * 8;
    const float* xj = xs + fj * XS_STRIDE + half * 8;
    f32x16 a0, a1;
#pragma unroll
    for (int s4 = 0; s4 < 4; ++s4) {
      float4 i0 = *(const float4*)(xi + s4 * 16);
      float4 i1 = *(const float4*)(xi + s4 * 16 + 4);
      float4 j0 = *(const float4*)(xj + s4 * 16);
      float4 j1 = *(const float4*)(xj + s4 * 16 + 4);
      ABFrag ip;
      ip.u[0] = pack2(i0.x * j0.x, i0.y * j0.y);
      ip.u[1] = pack2(i0.z * j0.z, i0.w * j0.w);
      ip.u[2] = pack2(i1.x * j1.x, i1.y * j1.y);
      ip.u[3] = pack2(i1.z * j1.z, i1.w * j1.w);
      if (s4 == 0) {
        a0 = __builtin_amdgcn_mfma_f32_32x32x16_bf16(fwh[0].v, ip.v, ABV, 0, 0, 0);
        a1 = __builtin_amdgcn_mfma_f32_32x32x16_bf16(fwl[0].v, ip.v, Z16, 0, 0, 0);
      } else {
        a0 = __builtin_amdgcn_mfma_f32_32x32x16_bf16(fwh[s4].v, ip.v, a0, 0, 0, 0);
        a1 = __builtin_amdgcn_mfma_f32_32x32x16_bf16(fwl[s4].v, ip.v, a1, 0, 0, 0);
      }
    }
    float lg = epi(a0, a1);
    if ((lane < 32) & !dpad) {
      float e = __expf(lg);
      Smh[fi * SM_STRIDE + fj] = bfbits_rn(e);
      lsum += e;
    }
  }
#pragma unroll
  for (int off = 1; off <= 32; off <<= 1) lsum += __shfl_xor(lsum, off);
  if (lane == 0) red[wid] = lsum;
  __syncthreads();  // B2: Smh scatter + lsum partials ready

  // ---- P4: M = S_up @ X via 16x16x32 MFMA; this wave handles d-quadrant
  // nt = wid. S rows/cols >=40 are zero: supplied from registers (not LDS).
  ABFrag fsh[3][2];
  const uint4 z4 = make_uint4(0u, 0u, 0u, 0u);
#pragma unroll
  for (int it = 0; it < 3; ++it) {
    const bool vr = (it < 2) | (col < 8);  // S row it*16+col < 40
    const unsigned short* srow = Smh + (it * 16 + col) * SM_STRIDE;
    fsh[it][0].q = vr ? *(const uint4*)(srow + quad * 8) : z4;           // k 0..31
    fsh[it][1].q = (vr & (quad == 0)) ? *(const uint4*)(srow + 32) : z4;  // k 32..39
  }
  const int dcol = wid * 16 + col;
  ABFrag fxh[2], fxl[2];
#pragma unroll
  for (int kt = 0; kt < 2; ++kt) {
    const int kbase = kt * 32 + quad * 8;
    if ((kt == 0) | (quad == 0)) {  // k < 40
#pragma unroll
      for (int p = 0; p < 4; ++p) {
        float v0 = xs[(kbase + 2 * p) * XS_STRIDE + dcol];
        float v1 = xs[(kbase + 2 * p + 1) * XS_STRIDE + dcol];
        split_pack(v0, v1, fxh[kt].u[p], fxl[kt].u[p]);
      }
    } else {
      fxh[kt].q = z4;
      fxl[kt].q = z4;
    }
  }
  f32x4 mac[3];
#pragma unroll
  for (int it = 0; it < 3; ++it) {
    f32x4 zh = {0.f, 0.f, 0.f, 0.f}, zl = {0.f, 0.f, 0.f, 0.f};  // 2 chains
    zh = __builtin_amdgcn_mfma_f32_16x16x32_bf16(fsh[it][0].v, fxh[0].v, zh, 0, 0, 0);
    zl = __builtin_amdgcn_mfma_f32_16x16x32_bf16(fsh[it][1].v, fxh[1].v, zl, 0, 0, 0);
    zh = __builtin_amdgcn_mfma_f32_16x16x32_bf16(fsh[it][0].v, fxl[0].v, zh, 0, 0, 0);
    zl = __builtin_amdgcn_mfma_f32_16x16x32_bf16(fsh[it][1].v, fxl[1].v, zl, 0, 0, 0);
    mac[it] = zh + zl;
  }
  float part = 0.f;
#pragma unroll
  for (int r = 0; r < 4; ++r)
    part = fmaf(mac[0][r], xs[(quad * 4 + r) * XS_STRIDE + dcol], part);
#pragma unroll
  for (int r = 0; r < 4; ++r)
    part = fmaf(mac[1][r], xs[(16 + quad * 4 + r) * XS_STRIDE + dcol], part);
  if (quad < 2) {
#pragma unroll
    for (int r = 0; r < 4; ++r)
      part = fmaf(mac[2][r], xs[(32 + quad * 4 + r) * XS_STRIDE + dcol], part);
  }
  part += __shfl_xor(part, 16);  // reduce over quads (i groups)
  part += __shfl_xor(part, 32);
  float ypart = part * fc_w[dcol];
#pragma unroll
  for (int off = 1; off <= 8; off <<= 1) ypart += __shfl_xor(ypart, off);
  if (lane == 0) red[4 + wid] = ypart;
  __syncthreads();  // B3: ypart partials ready

  if (tid == 0) {
    const float total = red[0] + red[1] + red[2] + red[3];
    out[row] = (red[4] + red[5] + red[6] + red[7]) / total + fcb;
  }
  (void)proj_b;  // cancels in softmax
}

extern "C" void kernel_launch(void* const* d_in, const int* in_sizes, int n_in,
                              void* d_out, int out_size, void* d_ws, size_t ws_size,
                              hipStream_t stream) {
  (void)in_sizes; (void)n_in; (void)out_size; (void)d_ws; (void)ws_size;
  afm_kernel<<<2048, 256, 0, stream>>>(
      (const float*)d_in[0], (const float*)d_in[1], (const float*)d_in[2],
      (const float*)d_in[3], (const float*)d_in[4], (const float*)d_in[5],
      (const float*)d_in[6], (float*)d_out);
}

// Round 4
// 95.037 us; speedup vs baseline: 1.0971x; 1.0971x over previous
//
#include <hip/hip_runtime.h>

// Round 17: dual-tile ILP, register-disciplined. Diagnosis across r14-r16:
// afm_kernel never appears in top-5 dispatches (all are 43us/268MB harness
// re-poison fills, 2 per iteration ~= 86us floor) => kernel is only ~7-13us
// of the ~97us bench. r16's +7us regression at 256 threads was VGPR spill
// (4 acc chains = 64 VGPRs + Z16 + dup frags). This round keeps r16's chain-
// halving idea at HALF the register cost, on the r14 base (1 wave/block, no
// barriers): two tiles in flight, ONE acc chain per tile (hi->lo interleaved,
// dep distance 2), rect pairs share the j operand (320 ds_read_b128 vs 400),
// Z16 gone. ~170 VGPR, no spill. P2 serial-unit count 25 -> 13.

#define NF 40
#define ED 64
#define AS 32
#define XS_STRIDE 68   // floats; 272 B rows, 16B-aligned, 4-bank rotate/row
#define SM_STRIDE 40   // shorts; 80 B rows, 16B-aligned, 20-bank rotate/row

typedef __attribute__((ext_vector_type(4))) float f32x4;
typedef __attribute__((ext_vector_type(16))) float f32x16;
typedef __attribute__((ext_vector_type(8))) short bf16x8;

union ABFrag { bf16x8 v; unsigned int u[4]; uint4 q; };

// bf16 round-half-up: bits(f)+0x8000 >> 16. == RNE except on exact ties.
__device__ __forceinline__ unsigned short bfbits_rn(float f) {
  return (unsigned short)((__float_as_uint(f) + 0x8000u) >> 16);
}
// pack2: (bf16(a)) | (bf16(b) << 16) in 3 VALU (2 adds + v_perm byte-pack).
__device__ __forceinline__ unsigned int pack2(float a, float b) {
  unsigned int ua = __float_as_uint(a) + 0x8000u;
  unsigned int ub = __float_as_uint(b) + 0x8000u;
  return __builtin_amdgcn_perm(ub, ua, 0x07060302u);
}
// split: hi = pack2(a,b); lo = pack2 of the exact residuals.
__device__ __forceinline__ void split_pack(float a, float b,
                                           unsigned int& hi, unsigned int& lo) {
  hi = pack2(a, b);
  float ra = a - __uint_as_float(hi << 16);
  float rb = b - __uint_as_float(hi & 0xffff0000u);
  lo = pack2(ra, rb);
}

__global__ __launch_bounds__(64, 2) void afm_kernel(
    const float* __restrict__ x, const float* __restrict__ attn_w,
    const float* __restrict__ attn_b, const float* __restrict__ proj_w,
    const float* __restrict__ proj_b, const float* __restrict__ fc_w,
    const float* __restrict__ fc_b, float* __restrict__ out) {
  __shared__ __align__(16) float xs[NF * XS_STRIDE];            // 10880 B
  __shared__ __align__(16) unsigned short Smh[NF * SM_STRIDE];  // 3200 B

  const int lane = threadIdx.x;      // one wave per block
  const int quad = lane >> 4;
  const int col = lane & 15;
  const int half = lane >> 5;        // 32x32 MFMA k-half
  const int m32 = lane & 31;         // 32x32 MFMA row/col index
  const int i_off = m32 >> 3;        // rect-tile row-within-tile
  const int jr_off = m32 & 7;        // rect-tile col-within-tile
  const int row = blockIdx.x;
  const float* xg = x + row * (NF * ED);

  // ---- P1: stage x row (10 float4/lane), zero Smh.
#pragma unroll
  for (int v = 0; v < 10; ++v) {
    int e4 = v * 64 + lane;           // 640 float4 per row
    int f = e4 >> 4, c4 = e4 & 15;
    *(float4*)(xs + f * XS_STRIDE + c4 * 4) = *(const float4*)(xg + e4 * 4);
  }
#pragma unroll
  for (int v = 0; v < 13; ++v) {      // 800 u32
    int e = v * 64 + lane;
    if (e < (NF * SM_STRIDE) / 2) ((unsigned int*)Smh)[e] = 0u;
  }

  // ---- per-lane constants.
  // A-frag (32x32x16): A[mrow=m32][k=half*8+e]; A = W^T -> w[d][a=m32].
  ABFrag fwh[4], fwl[4];
#pragma unroll
  for (int s4 = 0; s4 < 4; ++s4)
#pragma unroll
    for (int p = 0; p < 4; ++p) {
      int d = s4 * 16 + half * 8 + 2 * p;
      split_pack(attn_w[d * AS + m32], attn_w[(d + 1) * AS + m32],
                 fwh[s4].u[p], fwl[s4].u[p]);
    }
  // Epilogue constants: C/D row(reg) = (reg&3) + 8*(reg>>2) + 4*half.
  // ABV feeds the first MFMA C-operand of each tile chain (no acc-init movs).
  f32x16 ABV;
  float pwv[16];
#pragma unroll
  for (int r = 0; r < 16; ++r) {
    int arow = (r & 3) + 8 * (r >> 2) + 4 * half;
    ABV[r] = attn_b[arow];
    pwv[r] = proj_w[arow];
  }
  const float fcb = fc_b[0];

  // ---- diagonal-tile decode (once per lane): triu-of-8, 28 pairs + 4 pads.
  int dmm = (m32 < 28) ? m32 : 0;
  int da = 0;
  while (dmm >= 7 - da) { dmm -= 7 - da; ++da; }
  const int a_off = da;
  const int j_off = da + 1 + dmm;
  const bool dpad = (m32 >= 28);

  // ---- fused relu+proj epilogue: 4 independent 4-deep FMA chains.
  auto epi = [&](const f32x16& a) -> float {
    float lg0 = 0.f, lg1 = 0.f, lg2 = 0.f, lg3 = 0.f;
#pragma unroll
    for (int r = 0; r < 4; ++r) {
      lg0 = fmaf(fmaxf(a[r], 0.f), pwv[r], lg0);
      lg1 = fmaf(fmaxf(a[r + 4], 0.f), pwv[r + 4], lg1);
      lg2 = fmaf(fmaxf(a[r + 8], 0.f), pwv[r + 8], lg2);
      lg3 = fmaf(fmaxf(a[r + 12], 0.f), pwv[r + 12], lg3);
    }
    float lg = (lg0 + lg1) + (lg2 + lg3);
    lg += __shfl_xor(lg, 32);  // combine the two k-halves
    return lg;
  };

  float lsum = 0.f;

  // ---- dual-tile unit: two 32x32x16 MFMA tiles, ONE acc chain per tile
  // (hi then lo into same acc, dep distance 2 via A/B interleave). sharedJ
  // (rect pairs) skips tile B's j-loads; literal at call sites -> folded.
  auto do_pair = [&](int fiA, int fiB, int fjA, int fjB, bool sharedJ,
                     bool vA, bool vB) {
    const float* xiA = xs + fiA * XS_STRIDE + half * 8;
    const float* xiB = xs + fiB * XS_STRIDE + half * 8;
    const float* xjA = xs + fjA * XS_STRIDE + half * 8;
    const float* xjB = xs + fjB * XS_STRIDE + half * 8;
    f32x16 aA, aB;
#pragma unroll
    for (int s4 = 0; s4 < 4; ++s4) {
      float4 jA0 = *(const float4*)(xjA + s4 * 16);
      float4 jA1 = *(const float4*)(xjA + s4 * 16 + 4);
      float4 iA0 = *(const float4*)(xiA + s4 * 16);
      float4 iA1 = *(const float4*)(xiA + s4 * 16 + 4);
      float4 iB0 = *(const float4*)(xiB + s4 * 16);
      float4 iB1 = *(const float4*)(xiB + s4 * 16 + 4);
      float4 jB0, jB1;
      if (sharedJ) {
        jB0 = jA0; jB1 = jA1;
      } else {
        jB0 = *(const float4*)(xjB + s4 * 16);
        jB1 = *(const float4*)(xjB + s4 * 16 + 4);
      }
      ABFrag ipA, ipB;  // B-frags: B[k=half*8+e][n=m32]
      ipA.u[0] = pack2(iA0.x * jA0.x, iA0.y * jA0.y);
      ipA.u[1] = pack2(iA0.z * jA0.z, iA0.w * jA0.w);
      ipA.u[2] = pack2(iA1.x * jA1.x, iA1.y * jA1.y);
      ipA.u[3] = pack2(iA1.z * jA1.z, iA1.w * jA1.w);
      ipB.u[0] = pack2(iB0.x * jB0.x, iB0.y * jB0.y);
      ipB.u[1] = pack2(iB0.z * jB0.z, iB0.w * jB0.w);
      ipB.u[2] = pack2(iB1.x * jB1.x, iB1.y * jB1.y);
      ipB.u[3] = pack2(iB1.z * jB1.z, iB1.w * jB1.w);
      if (s4 == 0) {
        aA = __builtin_amdgcn_mfma_f32_32x32x16_bf16(fwh[0].v, ipA.v, ABV, 0, 0, 0);
        aB = __builtin_amdgcn_mfma_f32_32x32x16_bf16(fwh[0].v, ipB.v, ABV, 0, 0, 0);
        aA = __builtin_amdgcn_mfma_f32_32x32x16_bf16(fwl[0].v, ipA.v, aA, 0, 0, 0);
        aB = __builtin_amdgcn_mfma_f32_32x32x16_bf16(fwl[0].v, ipB.v, aB, 0, 0, 0);
      } else {
        aA = __builtin_amdgcn_mfma_f32_32x32x16_bf16(fwh[s4].v, ipA.v, aA, 0, 0, 0);
        aB = __builtin_amdgcn_mfma_f32_32x32x16_bf16(fwh[s4].v, ipB.v, aB, 0, 0, 0);
        aA = __builtin_amdgcn_mfma_f32_32x32x16_bf16(fwl[s4].v, ipA.v, aA, 0, 0, 0);
        aB = __builtin_amdgcn_mfma_f32_32x32x16_bf16(fwl[s4].v, ipB.v, aB, 0, 0, 0);
      }
    }
    float lgA = epi(aA);
    float lgB = epi(aB);
    if (vA) {
      float e = __expf(lgA);
      Smh[fiA * SM_STRIDE + fjA] = bfbits_rn(e);
      lsum += e;
    }
    if (vB) {
      float e = __expf(lgB);
      Smh[fiB * SM_STRIDE + fjB] = bfbits_rn(e);
      lsum += e;
    }
  };

  // ---- P2: 10 rect pairs (consecutive tiles share the j band) + 2 diag
  // pairs + 1 single diag tile. No max-subtract (|logit| << 88).
  for (int u = 0; u < 10; ++u) {
    const int t = 2 * u;
    const int j0 = 1 + (t >= 2) + (t >= 6) + (t >= 12);          // uniform
    const int tb = (t >= 12) ? 12 : (t >= 6) ? 6 : (t >= 2) ? 2 : 0;
    const int fiA = (t - tb) * 4 + i_off;
    const int fj = j0 * 8 + jr_off;
    do_pair(fiA, fiA + 4, fj, fj, true, lane < 32, lane < 32);
  }
  {
    const bool dv = (lane < 32) & !dpad;
    do_pair(a_off, 8 + a_off, j_off, 8 + j_off, false, dv, dv);          // chunks 0,1
    do_pair(16 + a_off, 24 + a_off, 16 + j_off, 24 + j_off, false, dv, dv);  // 2,3
  }
  {  // single diag tile (chunk 4)
    const int fi = 32 + a_off;
    const int fj = 32 + j_off;
    const float* xi = xs + fi * XS_STRIDE + half * 8;
    const float* xj = xs + fj * XS_STRIDE + half * 8;
    f32x16 a;
#pragma unroll
    for (int s4 = 0; s4 < 4; ++s4) {
      float4 i0 = *(const float4*)(xi + s4 * 16);
      float4 i1 = *(const float4*)(xi + s4 * 16 + 4);
      float4 j0 = *(const float4*)(xj + s4 * 16);
      float4 j1 = *(const float4*)(xj + s4 * 16 + 4);
      ABFrag ip;
      ip.u[0] = pack2(i0.x * j0.x, i0.y * j0.y);
      ip.u[1] = pack2(i0.z * j0.z, i0.w * j0.w);
      ip.u[2] = pack2(i1.x * j1.x, i1.y * j1.y);
      ip.u[3] = pack2(i1.z * j1.z, i1.w * j1.w);
      if (s4 == 0) {
        a = __builtin_amdgcn_mfma_f32_32x32x16_bf16(fwh[0].v, ip.v, ABV, 0, 0, 0);
        a = __builtin_amdgcn_mfma_f32_32x32x16_bf16(fwl[0].v, ip.v, a, 0, 0, 0);
      } else {
        a = __builtin_amdgcn_mfma_f32_32x32x16_bf16(fwh[s4].v, ip.v, a, 0, 0, 0);
        a = __builtin_amdgcn_mfma_f32_32x32x16_bf16(fwl[s4].v, ip.v, a, 0, 0, 0);
      }
    }
    float lg = epi(a);
    if ((lane < 32) & !dpad) {
      float e = __expf(lg);
      Smh[fi * SM_STRIDE + fj] = bfbits_rn(e);
      lsum += e;
    }
  }
#pragma unroll
  for (int off = 1; off <= 32; off <<= 1) lsum += __shfl_xor(lsum, off);
  const float total = lsum;  // this row's softmax denominator (all lanes)

  // ---- P4: M = S_up @ X via 16x16x32 MFMA; attn[d] = sum_i x_i[d]*M[i][d].
  // S rows >=40 and cols >=40 are zero: supplied from registers (not LDS).
  ABFrag fsh[3][2];
  const uint4 z4 = make_uint4(0u, 0u, 0u, 0u);
#pragma unroll
  for (int it = 0; it < 3; ++it) {
    const bool vr = (it < 2) | (col < 8);  // S row it*16+col < 40
    const unsigned short* srow = Smh + (it * 16 + col) * SM_STRIDE;
    fsh[it][0].q = vr ? *(const uint4*)(srow + quad * 8) : z4;           // k 0..31
    fsh[it][1].q = (vr & (quad == 0)) ? *(const uint4*)(srow + 32) : z4;  // k 32..39
  }
  float ypart = 0.f;
#pragma unroll
  for (int nt = 0; nt < 4; ++nt) {
    const int dcol = nt * 16 + col;
    ABFrag fxh[2], fxl[2];
#pragma unroll
    for (int kt = 0; kt < 2; ++kt) {
      const int kbase = kt * 32 + quad * 8;
      if ((kt == 0) | (quad == 0)) {  // k < 40
#pragma unroll
        for (int p = 0; p < 4; ++p) {
          float v0 = xs[(kbase + 2 * p) * XS_STRIDE + dcol];
          float v1 = xs[(kbase + 2 * p + 1) * XS_STRIDE + dcol];
          split_pack(v0, v1, fxh[kt].u[p], fxl[kt].u[p]);
        }
      } else {
        fxh[kt].q = z4;
        fxl[kt].q = z4;
      }
    }
    f32x4 mac[3];
#pragma unroll
    for (int it = 0; it < 3; ++it) {
      f32x4 zh = {0.f, 0.f, 0.f, 0.f}, zl = {0.f, 0.f, 0.f, 0.f};  // 2 chains
      zh = __builtin_amdgcn_mfma_f32_16x16x32_bf16(fsh[it][0].v, fxh[0].v, zh, 0, 0, 0);
      zl = __builtin_amdgcn_mfma_f32_16x16x32_bf16(fsh[it][1].v, fxh[1].v, zl, 0, 0, 0);
      zh = __builtin_amdgcn_mfma_f32_16x16x32_bf16(fsh[it][0].v, fxl[0].v, zh, 0, 0, 0);
      zl = __builtin_amdgcn_mfma_f32_16x16x32_bf16(fsh[it][1].v, fxl[1].v, zl, 0, 0, 0);
      mac[it] = zh + zl;
    }
    float part = 0.f;
#pragma unroll
    for (int r = 0; r < 4; ++r)
      part = fmaf(mac[0][r], xs[(quad * 4 + r) * XS_STRIDE + dcol], part);
#pragma unroll
    for (int r = 0; r < 4; ++r)
      part = fmaf(mac[1][r], xs[(16 + quad * 4 + r) * XS_STRIDE + dcol], part);
    if (quad < 2) {
#pragma unroll
      for (int r = 0; r < 4; ++r)
        part = fmaf(mac[2][r], xs[(32 + quad * 4 + r) * XS_STRIDE + dcol], part);
    }
    part += __shfl_xor(part, 16);  // reduce over quads (i groups)
    part += __shfl_xor(part, 32);
    ypart = fmaf(part, fc_w[dcol], ypart);
  }
#pragma unroll
  for (int off = 1; off <= 8; off <<= 1) ypart += __shfl_xor(ypart, off);
  if (lane == 0) out[row] = ypart / total + fcb;
  (void)proj_b;  // cancels in softmax
}

extern "C" void kernel_launch(void* const* d_in, const int* in_sizes, int n_in,
                              void* d_out, int out_size, void* d_ws, size_t ws_size,
                              hipStream_t stream) {
  (void)in_sizes; (void)n_in; (void)out_size; (void)d_ws; (void)ws_size;
  afm_kernel<<<2048, 64, 0, stream>>>(
      (const float*)d_in[0], (const float*)d_in[1], (const float*)d_in[2],
      (const float*)d_in[3], (const float*)d_in[4], (const float*)d_in[5],
      (const float*)d_in[6], (float*)d_out);
}

// Round 5
// 94.799 us; speedup vs baseline: 1.0999x; 1.0025x over previous
//
#include <hip/hip_runtime.h>

// Round 18: VALU-issue compression via CDNA4 packed ops. Model (r14-r17):
// bench = ~86us harness floor (2x 43us/268MB re-poison fills) + kernel
// (~9us). Kernel is VALU-issue bound: ~1950 product/pack VALU per lane in
// P2 at 2 waves/SIMD. This round: products via v_pk_mul_f32 (2 muls/inst),
// bf16 pair-pack via v_cvt_pk_bf16_f32 inline asm (1 inst vs pack2's 3,
// RNE vs half-up: differs on exact ties only), split_pack rebuilt on
// cvt_pk, relu+proj epilogue on f32x2 (v_pk_max/v_pk_fma candidates).
// ~-40% VALU per wave. Structure unchanged from r17 (dual-tile, 1 wave/
// block, no barriers, grid 2048x64, launch_bounds(64,2)).

#define NF 40
#define ED 64
#define AS 32
#define XS_STRIDE 68   // floats; 272 B rows, 16B-aligned, 4-bank rotate/row
#define SM_STRIDE 40   // shorts; 80 B rows, 16B-aligned, 20-bank rotate/row

typedef __attribute__((ext_vector_type(2))) float f32x2;
typedef __attribute__((ext_vector_type(4))) float f32x4;
typedef __attribute__((ext_vector_type(16))) float f32x16;
typedef __attribute__((ext_vector_type(8))) short bf16x8;

union ABFrag { bf16x8 v; unsigned int u[4]; uint4 q; };
union F4 { float4 f4; f32x2 h[2]; };

// bf16 round-half-up for the single-value Smh store.
__device__ __forceinline__ unsigned short bfbits_rn(float f) {
  return (unsigned short)((__float_as_uint(f) + 0x8000u) >> 16);
}
// One-instruction packed f32->bf16x2 (RNE). No builtin on gfx950 -> asm.
__device__ __forceinline__ unsigned int cvtpk(float a, float b) {
  unsigned int r;
  asm("v_cvt_pk_bf16_f32 %0, %1, %2" : "=v"(r) : "v"(a), "v"(b));
  return r;
}
// Packed product + packed convert: 2 insts for 2 products -> 1 bf16x2 word.
__device__ __forceinline__ unsigned int prodpack(f32x2 a, f32x2 b) {
  f32x2 p;
  asm("v_pk_mul_f32 %0, %1, %2" : "=v"(p) : "v"(a), "v"(b));
  return cvtpk(p.x, p.y);
}
// split: hi = cvtpk(a,b); lo = cvtpk of the exact residuals. 6 VALU.
__device__ __forceinline__ void split_pack(float a, float b,
                                           unsigned int& hi, unsigned int& lo) {
  hi = cvtpk(a, b);
  float ra = a - __uint_as_float(hi << 16);
  float rb = b - __uint_as_float(hi & 0xffff0000u);
  lo = cvtpk(ra, rb);
}

__global__ __launch_bounds__(64, 2) void afm_kernel(
    const float* __restrict__ x, const float* __restrict__ attn_w,
    const float* __restrict__ attn_b, const float* __restrict__ proj_w,
    const float* __restrict__ proj_b, const float* __restrict__ fc_w,
    const float* __restrict__ fc_b, float* __restrict__ out) {
  __shared__ __align__(16) float xs[NF * XS_STRIDE];            // 10880 B
  __shared__ __align__(16) unsigned short Smh[NF * SM_STRIDE];  // 3200 B

  const int lane = threadIdx.x;      // one wave per block
  const int quad = lane >> 4;
  const int col = lane & 15;
  const int half = lane >> 5;        // 32x32 MFMA k-half
  const int m32 = lane & 31;         // 32x32 MFMA row/col index
  const int i_off = m32 >> 3;        // rect-tile row-within-tile
  const int jr_off = m32 & 7;        // rect-tile col-within-tile
  const int row = blockIdx.x;
  const float* xg = x + row * (NF * ED);

  // ---- P1: stage x row (10 float4/lane), zero Smh.
#pragma unroll
  for (int v = 0; v < 10; ++v) {
    int e4 = v * 64 + lane;           // 640 float4 per row
    int f = e4 >> 4, c4 = e4 & 15;
    *(float4*)(xs + f * XS_STRIDE + c4 * 4) = *(const float4*)(xg + e4 * 4);
  }
#pragma unroll
  for (int v = 0; v < 13; ++v) {      // 800 u32
    int e = v * 64 + lane;
    if (e < (NF * SM_STRIDE) / 2) ((unsigned int*)Smh)[e] = 0u;
  }

  // ---- per-lane constants.
  // A-frag (32x32x16): A[mrow=m32][k=half*8+e]; A = W^T -> w[d][a=m32].
  ABFrag fwh[4], fwl[4];
#pragma unroll
  for (int s4 = 0; s4 < 4; ++s4)
#pragma unroll
    for (int p = 0; p < 4; ++p) {
      int d = s4 * 16 + half * 8 + 2 * p;
      split_pack(attn_w[d * AS + m32], attn_w[(d + 1) * AS + m32],
                 fwh[s4].u[p], fwl[s4].u[p]);
    }
  // Epilogue constants: C/D row(reg) = (reg&3) + 8*(reg>>2) + 4*half.
  // ABV feeds the first MFMA C-operand of each tile chain; pw2 holds proj_w
  // as f32x2 pairs matching adjacent acc regs (pk-fma epilogue).
  f32x16 ABV;
  f32x2 pw2[8];
#pragma unroll
  for (int r = 0; r < 16; ++r) {
    int arow = (r & 3) + 8 * (r >> 2) + 4 * half;
    ABV[r] = attn_b[arow];
    pw2[r >> 1][r & 1] = proj_w[arow];
  }
  const float fcb = fc_b[0];

  // ---- diagonal-tile decode (once per lane): triu-of-8, 28 pairs + 4 pads.
  int dmm = (m32 < 28) ? m32 : 0;
  int da = 0;
  while (dmm >= 7 - da) { dmm -= 7 - da; ++da; }
  const int a_off = da;
  const int j_off = da + 1 + dmm;
  const bool dpad = (m32 >= 28);

  // ---- fused relu+proj epilogue: 4 independent f32x2 chains (pk max/fma).
  auto epi = [&](const f32x16& a) -> float {
    f32x2 cc0 = {0.f, 0.f}, cc1 = {0.f, 0.f}, cc2 = {0.f, 0.f}, cc3 = {0.f, 0.f};
#pragma unroll
    for (int p = 0; p < 8; ++p) {
      f32x2 v = {a[2 * p], a[2 * p + 1]};
      f32x2 m = {fmaxf(v.x, 0.f), fmaxf(v.y, 0.f)};
      f32x2 t = m * pw2[p];
      if ((p & 3) == 0) cc0 += t;
      else if ((p & 3) == 1) cc1 += t;
      else if ((p & 3) == 2) cc2 += t;
      else cc3 += t;
    }
    f32x2 s = (cc0 + cc1) + (cc2 + cc3);
    float lg = s.x + s.y;
    lg += __shfl_xor(lg, 32);  // combine the two k-halves
    return lg;
  };

  float lsum = 0.f;

  // ---- dual-tile unit: two 32x32x16 MFMA tiles, ONE acc chain per tile
  // (hi then lo into same acc, dep distance 2 via A/B interleave). sharedJ
  // (rect pairs) skips tile B's j-loads; literal at call sites -> folded.
  auto do_pair = [&](int fiA, int fiB, int fjA, int fjB, bool sharedJ,
                     bool vA, bool vB) {
    const float* xiA = xs + fiA * XS_STRIDE + half * 8;
    const float* xiB = xs + fiB * XS_STRIDE + half * 8;
    const float* xjA = xs + fjA * XS_STRIDE + half * 8;
    const float* xjB = xs + fjB * XS_STRIDE + half * 8;
    f32x16 aA, aB;
#pragma unroll
    for (int s4 = 0; s4 < 4; ++s4) {
      F4 jA0, jA1, iA0, iA1, iB0, iB1, jB0, jB1;
      jA0.f4 = *(const float4*)(xjA + s4 * 16);
      jA1.f4 = *(const float4*)(xjA + s4 * 16 + 4);
      iA0.f4 = *(const float4*)(xiA + s4 * 16);
      iA1.f4 = *(const float4*)(xiA + s4 * 16 + 4);
      iB0.f4 = *(const float4*)(xiB + s4 * 16);
      iB1.f4 = *(const float4*)(xiB + s4 * 16 + 4);
      if (sharedJ) {
        jB0 = jA0; jB1 = jA1;
      } else {
        jB0.f4 = *(const float4*)(xjB + s4 * 16);
        jB1.f4 = *(const float4*)(xjB + s4 * 16 + 4);
      }
      ABFrag ipA, ipB;  // B-frags: B[k=half*8+e][n=m32]
      ipA.u[0] = prodpack(iA0.h[0], jA0.h[0]);
      ipA.u[1] = prodpack(iA0.h[1], jA0.h[1]);
      ipA.u[2] = prodpack(iA1.h[0], jA1.h[0]);
      ipA.u[3] = prodpack(iA1.h[1], jA1.h[1]);
      ipB.u[0] = prodpack(iB0.h[0], jB0.h[0]);
      ipB.u[1] = prodpack(iB0.h[1], jB0.h[1]);
      ipB.u[2] = prodpack(iB1.h[0], jB1.h[0]);
      ipB.u[3] = prodpack(iB1.h[1], jB1.h[1]);
      if (s4 == 0) {
        aA = __builtin_amdgcn_mfma_f32_32x32x16_bf16(fwh[0].v, ipA.v, ABV, 0, 0, 0);
        aB = __builtin_amdgcn_mfma_f32_32x32x16_bf16(fwh[0].v, ipB.v, ABV, 0, 0, 0);
        aA = __builtin_amdgcn_mfma_f32_32x32x16_bf16(fwl[0].v, ipA.v, aA, 0, 0, 0);
        aB = __builtin_amdgcn_mfma_f32_32x32x16_bf16(fwl[0].v, ipB.v, aB, 0, 0, 0);
      } else {
        aA = __builtin_amdgcn_mfma_f32_32x32x16_bf16(fwh[s4].v, ipA.v, aA, 0, 0, 0);
        aB = __builtin_amdgcn_mfma_f32_32x32x16_bf16(fwh[s4].v, ipB.v, aB, 0, 0, 0);
        aA = __builtin_amdgcn_mfma_f32_32x32x16_bf16(fwl[s4].v, ipA.v, aA, 0, 0, 0);
        aB = __builtin_amdgcn_mfma_f32_32x32x16_bf16(fwl[s4].v, ipB.v, aB, 0, 0, 0);
      }
    }
    float lgA = epi(aA);
    float lgB = epi(aB);
    if (vA) {
      float e = __expf(lgA);
      Smh[fiA * SM_STRIDE + fjA] = bfbits_rn(e);
      lsum += e;
    }
    if (vB) {
      float e = __expf(lgB);
      Smh[fiB * SM_STRIDE + fjB] = bfbits_rn(e);
      lsum += e;
    }
  };

  // ---- P2: 10 rect pairs (consecutive tiles share the j band) + 2 diag
  // pairs + 1 single diag tile. No max-subtract (|logit| << 88).
  for (int u = 0; u < 10; ++u) {
    const int t = 2 * u;
    const int j0 = 1 + (t >= 2) + (t >= 6) + (t >= 12);          // uniform
    const int tb = (t >= 12) ? 12 : (t >= 6) ? 6 : (t >= 2) ? 2 : 0;
    const int fiA = (t - tb) * 4 + i_off;
    const int fj = j0 * 8 + jr_off;
    do_pair(fiA, fiA + 4, fj, fj, true, lane < 32, lane < 32);
  }
  {
    const bool dv = (lane < 32) & !dpad;
    do_pair(a_off, 8 + a_off, j_off, 8 + j_off, false, dv, dv);          // chunks 0,1
    do_pair(16 + a_off, 24 + a_off, 16 + j_off, 24 + j_off, false, dv, dv);  // 2,3
  }
  {  // single diag tile (chunk 4)
    const int fi = 32 + a_off;
    const int fj = 32 + j_off;
    const float* xi = xs + fi * XS_STRIDE + half * 8;
    const float* xj = xs + fj * XS_STRIDE + half * 8;
    f32x16 a;
#pragma unroll
    for (int s4 = 0; s4 < 4; ++s4) {
      F4 i0, i1, j0, j1;
      i0.f4 = *(const float4*)(xi + s4 * 16);
      i1.f4 = *(const float4*)(xi + s4 * 16 + 4);
      j0.f4 = *(const float4*)(xj + s4 * 16);
      j1.f4 = *(const float4*)(xj + s4 * 16 + 4);
      ABFrag ip;
      ip.u[0] = prodpack(i0.h[0], j0.h[0]);
      ip.u[1] = prodpack(i0.h[1], j0.h[1]);
      ip.u[2] = prodpack(i1.h[0], j1.h[0]);
      ip.u[3] = prodpack(i1.h[1], j1.h[1]);
      if (s4 == 0) {
        a = __builtin_amdgcn_mfma_f32_32x32x16_bf16(fwh[0].v, ip.v, ABV, 0, 0, 0);
        a = __builtin_amdgcn_mfma_f32_32x32x16_bf16(fwl[0].v, ip.v, a, 0, 0, 0);
      } else {
        a = __builtin_amdgcn_mfma_f32_32x32x16_bf16(fwh[s4].v, ip.v, a, 0, 0, 0);
        a = __builtin_amdgcn_mfma_f32_32x32x16_bf16(fwl[s4].v, ip.v, a, 0, 0, 0);
      }
    }
    float lg = epi(a);
    if ((lane < 32) & !dpad) {
      float e = __expf(lg);
      Smh[fi * SM_STRIDE + fj] = bfbits_rn(e);
      lsum += e;
    }
  }
#pragma unroll
  for (int off = 1; off <= 32; off <<= 1) lsum += __shfl_xor(lsum, off);
  const float total = lsum;  // this row's softmax denominator (all lanes)

  // ---- P4: M = S_up @ X via 16x16x32 MFMA; attn[d] = sum_i x_i[d]*M[i][d].
  // S rows >=40 and cols >=40 are zero: supplied from registers (not LDS).
  ABFrag fsh[3][2];
  const uint4 z4 = make_uint4(0u, 0u, 0u, 0u);
#pragma unroll
  for (int it = 0; it < 3; ++it) {
    const bool vr = (it < 2) | (col < 8);  // S row it*16+col < 40
    const unsigned short* srow = Smh + (it * 16 + col) * SM_STRIDE;
    fsh[it][0].q = vr ? *(const uint4*)(srow + quad * 8) : z4;           // k 0..31
    fsh[it][1].q = (vr & (quad == 0)) ? *(const uint4*)(srow + 32) : z4;  // k 32..39
  }
  float ypart = 0.f;
#pragma unroll
  for (int nt = 0; nt < 4; ++nt) {
    const int dcol = nt * 16 + col;
    ABFrag fxh[2], fxl[2];
#pragma unroll
    for (int kt = 0; kt < 2; ++kt) {
      const int kbase = kt * 32 + quad * 8;
      if ((kt == 0) | (quad == 0)) {  // k < 40
#pragma unroll
        for (int p = 0; p < 4; ++p) {
          float v0 = xs[(kbase + 2 * p) * XS_STRIDE + dcol];
          float v1 = xs[(kbase + 2 * p + 1) * XS_STRIDE + dcol];
          split_pack(v0, v1, fxh[kt].u[p], fxl[kt].u[p]);
        }
      } else {
        fxh[kt].q = z4;
        fxl[kt].q = z4;
      }
    }
    f32x4 mac[3];
#pragma unroll
    for (int it = 0; it < 3; ++it) {
      f32x4 zh = {0.f, 0.f, 0.f, 0.f}, zl = {0.f, 0.f, 0.f, 0.f};  // 2 chains
      zh = __builtin_amdgcn_mfma_f32_16x16x32_bf16(fsh[it][0].v, fxh[0].v, zh, 0, 0, 0);
      zl = __builtin_amdgcn_mfma_f32_16x16x32_bf16(fsh[it][1].v, fxh[1].v, zl, 0, 0, 0);
      zh = __builtin_amdgcn_mfma_f32_16x16x32_bf16(fsh[it][0].v, fxl[0].v, zh, 0, 0, 0);
      zl = __builtin_amdgcn_mfma_f32_16x16x32_bf16(fsh[it][1].v, fxl[1].v, zl, 0, 0, 0);
      mac[it] = zh + zl;
    }
    float part = 0.f;
#pragma unroll
    for (int r = 0; r < 4; ++r)
      part = fmaf(mac[0][r], xs[(quad * 4 + r) * XS_STRIDE + dcol], part);
#pragma unroll
    for (int r = 0; r < 4; ++r)
      part = fmaf(mac[1][r], xs[(16 + quad * 4 + r) * XS_STRIDE + dcol], part);
    if (quad < 2) {
#pragma unroll
      for (int r = 0; r < 4; ++r)
        part = fmaf(mac[2][r], xs[(32 + quad * 4 + r) * XS_STRIDE + dcol], part);
    }
    part += __shfl_xor(part, 16);  // reduce over quads (i groups)
    part += __shfl_xor(part, 32);
    ypart = fmaf(part, fc_w[dcol], ypart);
  }
#pragma unroll
  for (int off = 1; off <= 8; off <<= 1) ypart += __shfl_xor(ypart, off);
  if (lane == 0) out[row] = ypart / total + fcb;
  (void)proj_b;  // cancels in softmax
}

extern "C" void kernel_launch(void* const* d_in, const int* in_sizes, int n_in,
                              void* d_out, int out_size, void* d_ws, size_t ws_size,
                              hipStream_t stream) {
  (void)in_sizes; (void)n_in; (void)out_size; (void)d_ws; (void)ws_size;
  afm_kernel<<<2048, 64, 0, stream>>>(
      (const float*)d_in[0], (const float*)d_in[1], (const float*)d_in[2],
      (const float*)d_in[3], (const float*)d_in[4], (const float*)d_in[5],
      (const float*)d_in[6], (float*)d_out);
}